// Round 5
// baseline (54.039 us; speedup 1.0000x reference)
//
#include <hip/hip_runtime.h>

namespace {

typedef float v4f __attribute__((ext_vector_type(4)));

struct M3 { float a[9]; };
struct V3 { float x, y, z; };

__device__ __forceinline__ V3 mulv_add(const M3& R, V3 o, V3 p) {
    V3 r;
    r.x = fmaf(R.a[0], o.x, fmaf(R.a[1], o.y, fmaf(R.a[2], o.z, p.x)));
    r.y = fmaf(R.a[3], o.x, fmaf(R.a[4], o.y, fmaf(R.a[5], o.z, p.y)));
    r.z = fmaf(R.a[6], o.x, fmaf(R.a[7], o.y, fmaf(R.a[8], o.z, p.z)));
    return r;
}

__device__ __forceinline__ M3 mulm(const M3& R, const M3& A) {
    M3 D;
#pragma unroll
    for (int i = 0; i < 3; ++i) {
#pragma unroll
        for (int k = 0; k < 3; ++k) {
            D.a[i*3+k] = fmaf(R.a[i*3+0], A.a[0*3+k],
                         fmaf(R.a[i*3+1], A.a[1*3+k],
                              R.a[i*3+2] * A.a[2*3+k]));
        }
    }
    return D;
}

template <int REL>
__device__ __forceinline__ float getf(const float4* s) {
    constexpr int Q = REL >> 2;
    constexpr int C = REL & 3;
    if constexpr (C == 0) return s[Q].x;
    else if constexpr (C == 1) return s[Q].y;
    else if constexpr (C == 2) return s[Q].z;
    else return s[Q].w;
}

template <int J, int BASE>
__device__ __forceinline__ M3 loadA(const float4* s) {
    constexpr int K = 9 * J - BASE;
    M3 A;
    A.a[0] = getf<K+0>(s); A.a[1] = getf<K+1>(s); A.a[2] = getf<K+2>(s);
    A.a[3] = getf<K+3>(s); A.a[4] = getf<K+4>(s); A.a[5] = getf<K+5>(s);
    A.a[6] = getf<K+6>(s); A.a[7] = getf<K+7>(s); A.a[8] = getf<K+8>(s);
    return A;
}

__device__ __forceinline__ V3 loadOff(const float* __restrict__ off, int j) {
    V3 o; o.x = off[3*j+0]; o.y = off[3*j+1]; o.z = off[3*j+2]; return o;
}

// async global->LDS, 16B per lane; dst is the WAVE-UNIFORM base (HW adds lane*16)
__device__ __forceinline__ void gload16(const float4* src, float4* lds_base) {
    __builtin_amdgcn_global_load_lds(
        (const __attribute__((address_space(1))) void*)src,
        (__attribute__((address_space(3))) void*)lds_base, 16, 0, 0);
}

#define OBP(J, P) do { ob[3*(J)+0] = (P).x; ob[3*(J)+1] = (P).y; ob[3*(J)+2] = (P).z; } while (0)

// one wave (64 samples) per block; 43 KB LDS -> 3 blocks/CU
__global__ __launch_bounds__(64)
void fk_kernel(const float* __restrict__ ja, const float* __restrict__ off,
               float* __restrict__ out) {
    // single array so the compiler treats A1/stage overlap as may-alias
    __shared__ __align__(16) float4 lds[2688];     // 43,008 B
    float4* A1 = lds;            // [64][21]  span1: row f4s [2,23)   (A_1..A_9)
    float4* A2 = lds + 1344;     // [64][7]   span2: row f4s [27,34)  (A_12..A_14)
    float4* A3 = lds + 1792;     // [64][14]  span3: row f4s [36,50)  (A_16..A_21)
    float4* stage = lds;         // reuse A1 region as [18][65] output stage

    const int l = threadIdx.x;                       // 0..63
    const size_t blockBase = (size_t)blockIdx.x * 64;
    const float4* g = reinterpret_cast<const float4*>(ja) + blockBase * 54;

    // ---- coalesced gathers: packed index p -> (sample s, span elem j) ----
#pragma unroll
    for (int k = 0; k < 21; ++k) {                   // span1: 64*21 f4
        int p = k * 64 + l;
        int s = p / 21, j = p - s * 21;              // magic-mul div
        gload16(g + s * 54 + 2 + j, A1 + k * 64);
    }
#pragma unroll
    for (int k = 0; k < 7; ++k) {                    // span2: 64*7 f4
        int p = k * 64 + l;
        int s = p / 7, j = p - s * 7;
        gload16(g + s * 54 + 27 + j, A2 + k * 64);
    }
#pragma unroll
    for (int k = 0; k < 14; ++k) {                   // span3: 64*14 f4
        int p = k * 64 + l;
        int s = p / 14, j = p - s * 14;
        gload16(g + s * 54 + 36 + j, A3 + k * 64);
    }

    float ob[72];
    ob[0] = 0.f; ob[1] = 0.f; ob[2] = 0.f;           // root position

    // ---- span1 ready (first 21 loads retire in issue order) ----
    asm volatile("s_waitcnt vmcnt(21)" ::: "memory");

    float4 s1[21];
    {
        const float4* r1 = A1 + l * 21;              // quad-stride 5 (odd): conflict-free
#pragma unroll
        for (int c = 0; c < 21; ++c) s1[c] = r1[c];
    }
    constexpr int B1 = 8, B2 = 108, B3 = 144;

    V3 p1 = loadOff(off, 1), p2 = loadOff(off, 2), p3 = loadOff(off, 3);
    OBP(1, p1); OBP(2, p2); OBP(3, p3);
    M3 R1 = loadA<1, B1>(s1);
    M3 R2 = loadA<2, B1>(s1);
    M3 R3 = loadA<3, B1>(s1);

    V3 p4 = mulv_add(R1, loadOff(off, 4), p1);  M3 R4 = mulm(R1, loadA<4, B1>(s1));  OBP(4, p4);
    V3 p5 = mulv_add(R2, loadOff(off, 5), p2);  M3 R5 = mulm(R2, loadA<5, B1>(s1));  OBP(5, p5);
    V3 p6 = mulv_add(R3, loadOff(off, 6), p3);  M3 R6 = mulm(R3, loadA<6, B1>(s1));  OBP(6, p6);
    V3 p7 = mulv_add(R4, loadOff(off, 7), p4);  M3 R7 = mulm(R4, loadA<7, B1>(s1));  OBP(7, p7);
    V3 p8 = mulv_add(R5, loadOff(off, 8), p5);  M3 R8 = mulm(R5, loadA<8, B1>(s1));  OBP(8, p8);
    V3 p9 = mulv_add(R6, loadOff(off, 9), p6);  M3 R9 = mulm(R6, loadA<9, B1>(s1));  OBP(9, p9);

    V3 p10 = mulv_add(R7, loadOff(off, 10), p7);  OBP(10, p10);   // leaf
    V3 p11 = mulv_add(R8, loadOff(off, 11), p8);  OBP(11, p11);   // leaf

    // ---- span2 ready ----
    asm volatile("s_waitcnt vmcnt(14)" ::: "memory");
    float4 s2[7];
    {
        const float4* r2 = A2 + l * 7;               // quad-stride 7 (odd): conflict-free
#pragma unroll
        for (int c = 0; c < 7; ++c) s2[c] = r2[c];
    }

    V3 p12 = mulv_add(R9, loadOff(off, 12), p9);  M3 R12 = mulm(R9, loadA<12, B2>(s2));  OBP(12, p12);
    V3 p13 = mulv_add(R9, loadOff(off, 13), p9);  M3 R13 = mulm(R9, loadA<13, B2>(s2));  OBP(13, p13);
    V3 p14 = mulv_add(R9, loadOff(off, 14), p9);  M3 R14 = mulm(R9, loadA<14, B2>(s2));  OBP(14, p14);
    V3 p15 = mulv_add(R12, loadOff(off, 15), p12);  OBP(15, p15); // head leaf

    // ---- span3 ready ----
    asm volatile("s_waitcnt vmcnt(0)" ::: "memory");
    float4 s3[14];
    {
        const float4* r3 = A3 + l * 14;              // quad-stride 6: 2-way (free)
#pragma unroll
        for (int c = 0; c < 14; ++c) s3[c] = r3[c];
    }

    V3 p16 = mulv_add(R13, loadOff(off, 16), p13);  M3 R16 = mulm(R13, loadA<16, B3>(s3));  OBP(16, p16);
    V3 p17 = mulv_add(R14, loadOff(off, 17), p14);  M3 R17 = mulm(R14, loadA<17, B3>(s3));  OBP(17, p17);
    V3 p18 = mulv_add(R16, loadOff(off, 18), p16);  M3 R18 = mulm(R16, loadA<18, B3>(s3));  OBP(18, p18);
    V3 p19 = mulv_add(R17, loadOff(off, 19), p17);  M3 R19 = mulm(R17, loadA<19, B3>(s3));  OBP(19, p19);
    V3 p20 = mulv_add(R18, loadOff(off, 20), p18);  M3 R20 = mulm(R18, loadA<20, B3>(s3));  OBP(20, p20);
    V3 p21 = mulv_add(R19, loadOff(off, 21), p19);  M3 R21 = mulm(R19, loadA<21, B3>(s3));  OBP(21, p21);

    V3 p22 = mulv_add(R20, loadOff(off, 22), p20);  OBP(22, p22); // hand leaf
    V3 p23 = mulv_add(R21, loadOff(off, 23), p21);  OBP(23, p23); // hand leaf

    // ---- transpose via LDS (reuses span1 region; same wave, in-order DS) ----
    asm volatile("" ::: "memory");
#pragma unroll
    for (int r = 0; r < 18; ++r) {
        float4 v;
        v.x = ob[4*r+0]; v.y = ob[4*r+1]; v.z = ob[4*r+2]; v.w = ob[4*r+3];
        stage[r * 65 + l] = v;                       // quad (r+l)%8: uniform, free
    }

    // ---- coalesced nontemporal output ----
    v4f* o4 = reinterpret_cast<v4f*>(out);
    const size_t base4 = blockBase * 18;
#pragma unroll
    for (int i = 0; i < 18; ++i) {
        int e4 = i * 64 + l;
        int s  = e4 / 18;                            // magic-mul div
        int r  = e4 - s * 18;
        float4 v = stage[r * 65 + s];
        v4f vv; vv.x = v.x; vv.y = v.y; vv.z = v.z; vv.w = v.w;
        __builtin_nontemporal_store(vv, &o4[base4 + e4]);
    }
}

}  // namespace

extern "C" void kernel_launch(void* const* d_in, const int* in_sizes, int n_in,
                              void* d_out, int out_size, void* d_ws, size_t ws_size,
                              hipStream_t stream) {
    const float* ja  = (const float*)d_in[0];
    const float* off = (const float*)d_in[1];
    float* out = (float*)d_out;

    int N = in_sizes[0] / 216;     // 262144
    int grid = N / 64;             // 4096 one-wave blocks
    hipLaunchKernelGGL(fk_kernel, dim3(grid), dim3(64), 0, stream, ja, off, out);
}

// Round 6
// 53.299 us; speedup vs baseline: 1.0139x; 1.0139x over previous
//
#include <hip/hip_runtime.h>

namespace {

typedef float v4f __attribute__((ext_vector_type(4)));

struct M3 { float a[9]; };
struct V3 { float x, y, z; };

__device__ __forceinline__ V3 mulv_add(const M3& R, V3 o, V3 p) {
    V3 r;
    r.x = fmaf(R.a[0], o.x, fmaf(R.a[1], o.y, fmaf(R.a[2], o.z, p.x)));
    r.y = fmaf(R.a[3], o.x, fmaf(R.a[4], o.y, fmaf(R.a[5], o.z, p.y)));
    r.z = fmaf(R.a[6], o.x, fmaf(R.a[7], o.y, fmaf(R.a[8], o.z, p.z)));
    return r;
}

__device__ __forceinline__ M3 mulm(const M3& R, const M3& A) {
    M3 D;
#pragma unroll
    for (int i = 0; i < 3; ++i) {
#pragma unroll
        for (int k = 0; k < 3; ++k) {
            D.a[i*3+k] = fmaf(R.a[i*3+0], A.a[0*3+k],
                         fmaf(R.a[i*3+1], A.a[1*3+k],
                              R.a[i*3+2] * A.a[2*3+k]));
        }
    }
    return D;
}

template <int REL>
__device__ __forceinline__ float getf(const float4* s) {
    constexpr int Q = REL >> 2;
    constexpr int C = REL & 3;
    if constexpr (C == 0) return s[Q].x;
    else if constexpr (C == 1) return s[Q].y;
    else if constexpr (C == 2) return s[Q].z;
    else return s[Q].w;
}

template <int J, int BASE>
__device__ __forceinline__ M3 loadA(const float4* s) {
    constexpr int K = 9 * J - BASE;
    M3 A;
    A.a[0] = getf<K+0>(s); A.a[1] = getf<K+1>(s); A.a[2] = getf<K+2>(s);
    A.a[3] = getf<K+3>(s); A.a[4] = getf<K+4>(s); A.a[5] = getf<K+5>(s);
    A.a[6] = getf<K+6>(s); A.a[7] = getf<K+7>(s); A.a[8] = getf<K+8>(s);
    return A;
}

__device__ __forceinline__ V3 loadOff(const float* __restrict__ off, int j) {
    V3 o; o.x = off[3*j+0]; o.y = off[3*j+1]; o.z = off[3*j+2]; return o;
}

// async global->LDS, 16B per lane; dst is the WAVE-UNIFORM base (HW adds lane*16)
__device__ __forceinline__ void gload16(const float4* src, float4* lds_base) {
    __builtin_amdgcn_global_load_lds(
        (const __attribute__((address_space(1))) void*)src,
        (__attribute__((address_space(3))) void*)lds_base, 16, 0, 0);
}

#define OBP(J, P) do { ob[3*(J)+0] = (P).x; ob[3*(J)+1] = (P).y; ob[3*(J)+2] = (P).z; } while (0)

// one wave (64 samples) per block; 43 KB LDS -> 3 blocks/CU
__global__ __launch_bounds__(64)
void fk_kernel(const float* __restrict__ ja, const float* __restrict__ off,
               float* __restrict__ out) {
    __shared__ __align__(16) float4 lds[2688];     // 43,008 B
    float4* A1 = lds;            // [64][21]  span1: row f4s [2,23)   (A_1..A_9)
    float4* A2 = lds + 1344;     // [64][7]   span2: row f4s [27,34)  (A_12..A_14)
    float4* A3 = lds + 1792;     // [64][14]  span3: row f4s [36,50)  (A_16..A_21)
    float4* stage = lds;         // reuse A1 region as [18][65] output stage

    const int l = threadIdx.x;                       // 0..63
    const size_t blockBase = (size_t)blockIdx.x * 64;
    const float4* g = reinterpret_cast<const float4*>(ja) + blockBase * 54;

    // ---- coalesced gathers, issued in globally ASCENDING address order ----
    // (merge-sorted by each instruction's lane-0 address: one sweep over the
    //  55 KB window -> same-page requests arrive adjacent at the memory
    //  controller -> ~1 activate/page instead of 2-3)
    auto issue1 = [&](int k) { int p = k*64 + l; int s = p/21, j = p - s*21;
                               gload16(g + s*54 +  2 + j, A1 + k*64); };
    auto issue2 = [&](int k) { int p = k*64 + l; int s = p/7,  j = p - s*7;
                               gload16(g + s*54 + 27 + j, A2 + k*64); };
    auto issue3 = [&](int k) { int p = k*64 + l; int s = p/14, j = p - s*14;
                               gload16(g + s*54 + 36 + j, A3 + k*64); };

    issue1(0);  issue2(0); issue3(0);  issue1(1);  issue3(1);  issue1(2);
    issue1(3);  issue2(1); issue3(2);  issue1(4);  issue3(3);  issue1(5);
    issue1(6);  issue2(2); issue3(4);  issue1(7);  issue3(5);  issue1(8);
    issue1(9);  issue2(3); issue3(6);  issue1(10); issue3(7);  issue1(11);
    issue1(12); issue2(4); issue3(8);  issue1(13); issue3(9);  issue1(14);
    issue1(15); issue2(5); issue3(10); issue1(16); issue3(11); issue1(17);
    issue1(18); issue2(6); issue3(12); issue1(19); issue3(13); issue1(20);

    float ob[72];
    ob[0] = 0.f; ob[1] = 0.f; ob[2] = 0.f;           // root position

    // span1 completes last in merged order: single full drain
    asm volatile("s_waitcnt vmcnt(0)" ::: "memory");

    float4 s1[21];
    {
        const float4* r1 = A1 + l * 21;              // quad-stride 5 (odd): conflict-free
#pragma unroll
        for (int c = 0; c < 21; ++c) s1[c] = r1[c];
    }
    constexpr int B1 = 8, B2 = 108, B3 = 144;

    V3 p1 = loadOff(off, 1), p2 = loadOff(off, 2), p3 = loadOff(off, 3);
    OBP(1, p1); OBP(2, p2); OBP(3, p3);
    M3 R1 = loadA<1, B1>(s1);
    M3 R2 = loadA<2, B1>(s1);
    M3 R3 = loadA<3, B1>(s1);

    V3 p4 = mulv_add(R1, loadOff(off, 4), p1);  M3 R4 = mulm(R1, loadA<4, B1>(s1));  OBP(4, p4);
    V3 p5 = mulv_add(R2, loadOff(off, 5), p2);  M3 R5 = mulm(R2, loadA<5, B1>(s1));  OBP(5, p5);
    V3 p6 = mulv_add(R3, loadOff(off, 6), p3);  M3 R6 = mulm(R3, loadA<6, B1>(s1));  OBP(6, p6);
    V3 p7 = mulv_add(R4, loadOff(off, 7), p4);  M3 R7 = mulm(R4, loadA<7, B1>(s1));  OBP(7, p7);
    V3 p8 = mulv_add(R5, loadOff(off, 8), p5);  M3 R8 = mulm(R5, loadA<8, B1>(s1));  OBP(8, p8);
    V3 p9 = mulv_add(R6, loadOff(off, 9), p6);  M3 R9 = mulm(R6, loadA<9, B1>(s1));  OBP(9, p9);

    V3 p10 = mulv_add(R7, loadOff(off, 10), p7);  OBP(10, p10);   // leaf
    V3 p11 = mulv_add(R8, loadOff(off, 11), p8);  OBP(11, p11);   // leaf

    float4 s2[7];
    {
        const float4* r2 = A2 + l * 7;               // quad-stride 7 (odd): conflict-free
#pragma unroll
        for (int c = 0; c < 7; ++c) s2[c] = r2[c];
    }

    V3 p12 = mulv_add(R9, loadOff(off, 12), p9);  M3 R12 = mulm(R9, loadA<12, B2>(s2));  OBP(12, p12);
    V3 p13 = mulv_add(R9, loadOff(off, 13), p9);  M3 R13 = mulm(R9, loadA<13, B2>(s2));  OBP(13, p13);
    V3 p14 = mulv_add(R9, loadOff(off, 14), p9);  M3 R14 = mulm(R9, loadA<14, B2>(s2));  OBP(14, p14);
    V3 p15 = mulv_add(R12, loadOff(off, 15), p12);  OBP(15, p15); // head leaf

    float4 s3[14];
    {
        const float4* r3 = A3 + l * 14;              // quad-stride 6: 2-way (free)
#pragma unroll
        for (int c = 0; c < 14; ++c) s3[c] = r3[c];
    }

    V3 p16 = mulv_add(R13, loadOff(off, 16), p13);  M3 R16 = mulm(R13, loadA<16, B3>(s3));  OBP(16, p16);
    V3 p17 = mulv_add(R14, loadOff(off, 17), p14);  M3 R17 = mulm(R14, loadA<17, B3>(s3));  OBP(17, p17);
    V3 p18 = mulv_add(R16, loadOff(off, 18), p16);  M3 R18 = mulm(R16, loadA<18, B3>(s3));  OBP(18, p18);
    V3 p19 = mulv_add(R17, loadOff(off, 19), p17);  M3 R19 = mulm(R17, loadA<19, B3>(s3));  OBP(19, p19);
    V3 p20 = mulv_add(R18, loadOff(off, 20), p18);  M3 R20 = mulm(R18, loadA<20, B3>(s3));  OBP(20, p20);
    V3 p21 = mulv_add(R19, loadOff(off, 21), p19);  M3 R21 = mulm(R19, loadA<21, B3>(s3));  OBP(21, p21);

    V3 p22 = mulv_add(R20, loadOff(off, 22), p20);  OBP(22, p22); // hand leaf
    V3 p23 = mulv_add(R21, loadOff(off, 23), p21);  OBP(23, p23); // hand leaf

    // ---- transpose via LDS (reuses span1 region; same wave, in-order DS) ----
    asm volatile("" ::: "memory");
#pragma unroll
    for (int r = 0; r < 18; ++r) {
        float4 v;
        v.x = ob[4*r+0]; v.y = ob[4*r+1]; v.z = ob[4*r+2]; v.w = ob[4*r+3];
        stage[r * 65 + l] = v;                       // quad (r+l)%8: uniform, free
    }

    // ---- coalesced nontemporal output ----
    v4f* o4 = reinterpret_cast<v4f*>(out);
    const size_t base4 = blockBase * 18;
#pragma unroll
    for (int i = 0; i < 18; ++i) {
        int e4 = i * 64 + l;
        int s  = e4 / 18;                            // magic-mul div
        int r  = e4 - s * 18;
        float4 v = stage[r * 65 + s];
        v4f vv; vv.x = v.x; vv.y = v.y; vv.z = v.z; vv.w = v.w;
        __builtin_nontemporal_store(vv, &o4[base4 + e4]);
    }
}

}  // namespace

extern "C" void kernel_launch(void* const* d_in, const int* in_sizes, int n_in,
                              void* d_out, int out_size, void* d_ws, size_t ws_size,
                              hipStream_t stream) {
    const float* ja  = (const float*)d_in[0];
    const float* off = (const float*)d_in[1];
    float* out = (float*)d_out;

    int N = in_sizes[0] / 216;     // 262144
    int grid = N / 64;             // 4096 one-wave blocks
    hipLaunchKernelGGL(fk_kernel, dim3(grid), dim3(64), 0, stream, ja, off, out);
}

// Round 7
// 51.457 us; speedup vs baseline: 1.0502x; 1.0358x over previous
//
#include <hip/hip_runtime.h>

namespace {

typedef float v4f __attribute__((ext_vector_type(4)));

struct M3 { float a[9]; };
struct V3 { float x, y, z; };

__device__ __forceinline__ V3 mulv_add(const M3& R, V3 o, V3 p) {
    V3 r;
    r.x = fmaf(R.a[0], o.x, fmaf(R.a[1], o.y, fmaf(R.a[2], o.z, p.x)));
    r.y = fmaf(R.a[3], o.x, fmaf(R.a[4], o.y, fmaf(R.a[5], o.z, p.y)));
    r.z = fmaf(R.a[6], o.x, fmaf(R.a[7], o.y, fmaf(R.a[8], o.z, p.z)));
    return r;
}

__device__ __forceinline__ M3 mulm(const M3& R, const M3& A) {
    M3 D;
#pragma unroll
    for (int i = 0; i < 3; ++i) {
#pragma unroll
        for (int k = 0; k < 3; ++k) {
            D.a[i*3+k] = fmaf(R.a[i*3+0], A.a[0*3+k],
                         fmaf(R.a[i*3+1], A.a[1*3+k],
                              R.a[i*3+2] * A.a[2*3+k]));
        }
    }
    return D;
}

template <int REL>
__device__ __forceinline__ float getf(const float4* s) {
    constexpr int Q = REL >> 2;
    constexpr int C = REL & 3;
    if constexpr (C == 0) return s[Q].x;
    else if constexpr (C == 1) return s[Q].y;
    else if constexpr (C == 2) return s[Q].z;
    else return s[Q].w;
}

template <int J, int BASE>
__device__ __forceinline__ M3 loadA(const float4* s) {
    constexpr int K = 9 * J - BASE;
    M3 A;
    A.a[0] = getf<K+0>(s); A.a[1] = getf<K+1>(s); A.a[2] = getf<K+2>(s);
    A.a[3] = getf<K+3>(s); A.a[4] = getf<K+4>(s); A.a[5] = getf<K+5>(s);
    A.a[6] = getf<K+6>(s); A.a[7] = getf<K+7>(s); A.a[8] = getf<K+8>(s);
    return A;
}

__device__ __forceinline__ V3 loadOff(const float* __restrict__ off, int j) {
    V3 o; o.x = off[3*j+0]; o.y = off[3*j+1]; o.z = off[3*j+2]; return o;
}

// async global->LDS, 16B per lane; dst is the WAVE-UNIFORM base (HW adds lane*16)
__device__ __forceinline__ void gload16(const float4* src, float4* lds_base) {
    __builtin_amdgcn_global_load_lds(
        (const __attribute__((address_space(1))) void*)src,
        (__attribute__((address_space(3))) void*)lds_base, 16, 0, 0);
}

#define OBP(J, P) do { ob[3*(J)+0] = (P).x; ob[3*(J)+1] = (P).y; ob[3*(J)+2] = (P).z; } while (0)

// one wave per block; LDS = 21.5 KB (span1, reused as output stage) -> 7 blocks/CU
__global__ __launch_bounds__(64, 2)
void fk_kernel(const float* __restrict__ ja, const float* __restrict__ off,
               float* __restrict__ out) {
    __shared__ __align__(16) float4 lds[1344];   // 21,504 B
    float4* A1 = lds;        // [64][21]  span1: row f4s [2,23)  (A_1..A_9)
    float4* stage = lds;     // reused as [18][65] output stage (1170 <= 1344)

    const int l = threadIdx.x;                       // 0..63
    const size_t blockBase = (size_t)blockIdx.x * 64;
    const float4* g = reinterpret_cast<const float4*>(ja) + blockBase * 54;
    const float4* row = g + (size_t)l * 54;

    // ---- spans 2+3 per-lane into registers, issued FIRST (longest overlap) ----
    float4 s2[7];    // row f4s [27,34)  (A_12..A_14)
#pragma unroll
    for (int c = 0; c < 7; ++c) s2[c] = row[27 + c];
    float4 s3[14];   // row f4s [36,50)  (A_16..A_21)
#pragma unroll
    for (int c = 0; c < 14; ++c) s3[c] = row[36 + c];

    // ---- span1 coalesced via global_load_lds (packed index, magic-mul div) ----
#pragma unroll
    for (int k = 0; k < 21; ++k) {
        int p = k * 64 + l;
        int s = p / 21, j = p - s * 21;
        gload16(g + s * 54 + 2 + j, A1 + k * 64);
    }

    float ob[72];
    ob[0] = 0.f; ob[1] = 0.f; ob[2] = 0.f;           // root position

    // all loads drained (reg loads issued first retire first anyway)
    asm volatile("s_waitcnt vmcnt(0)" ::: "memory");

    float4 s1[21];
    {
        const float4* r1 = A1 + l * 21;              // quad-stride 5 (odd): conflict-free
#pragma unroll
        for (int c = 0; c < 21; ++c) s1[c] = r1[c];
    }
    constexpr int B1 = 8, B2 = 108, B3 = 144;

    V3 p1 = loadOff(off, 1), p2 = loadOff(off, 2), p3 = loadOff(off, 3);
    OBP(1, p1); OBP(2, p2); OBP(3, p3);
    M3 R1 = loadA<1, B1>(s1);
    M3 R2 = loadA<2, B1>(s1);
    M3 R3 = loadA<3, B1>(s1);

    V3 p4 = mulv_add(R1, loadOff(off, 4), p1);  M3 R4 = mulm(R1, loadA<4, B1>(s1));  OBP(4, p4);
    V3 p5 = mulv_add(R2, loadOff(off, 5), p2);  M3 R5 = mulm(R2, loadA<5, B1>(s1));  OBP(5, p5);
    V3 p6 = mulv_add(R3, loadOff(off, 6), p3);  M3 R6 = mulm(R3, loadA<6, B1>(s1));  OBP(6, p6);
    V3 p7 = mulv_add(R4, loadOff(off, 7), p4);  M3 R7 = mulm(R4, loadA<7, B1>(s1));  OBP(7, p7);
    V3 p8 = mulv_add(R5, loadOff(off, 8), p5);  M3 R8 = mulm(R5, loadA<8, B1>(s1));  OBP(8, p8);
    V3 p9 = mulv_add(R6, loadOff(off, 9), p6);  M3 R9 = mulm(R6, loadA<9, B1>(s1));  OBP(9, p9);

    V3 p10 = mulv_add(R7, loadOff(off, 10), p7);  OBP(10, p10);   // leaf
    V3 p11 = mulv_add(R8, loadOff(off, 11), p8);  OBP(11, p11);   // leaf

    V3 p12 = mulv_add(R9, loadOff(off, 12), p9);  M3 R12 = mulm(R9, loadA<12, B2>(s2));  OBP(12, p12);
    V3 p13 = mulv_add(R9, loadOff(off, 13), p9);  M3 R13 = mulm(R9, loadA<13, B2>(s2));  OBP(13, p13);
    V3 p14 = mulv_add(R9, loadOff(off, 14), p9);  M3 R14 = mulm(R9, loadA<14, B2>(s2));  OBP(14, p14);
    V3 p15 = mulv_add(R12, loadOff(off, 15), p12);  OBP(15, p15); // head leaf

    V3 p16 = mulv_add(R13, loadOff(off, 16), p13);  M3 R16 = mulm(R13, loadA<16, B3>(s3));  OBP(16, p16);
    V3 p17 = mulv_add(R14, loadOff(off, 17), p14);  M3 R17 = mulm(R14, loadA<17, B3>(s3));  OBP(17, p17);
    V3 p18 = mulv_add(R16, loadOff(off, 18), p16);  M3 R18 = mulm(R16, loadA<18, B3>(s3));  OBP(18, p18);
    V3 p19 = mulv_add(R17, loadOff(off, 19), p17);  M3 R19 = mulm(R17, loadA<19, B3>(s3));  OBP(19, p19);
    V3 p20 = mulv_add(R18, loadOff(off, 20), p18);  M3 R20 = mulm(R18, loadA<20, B3>(s3));  OBP(20, p20);
    V3 p21 = mulv_add(R19, loadOff(off, 21), p19);  M3 R21 = mulm(R19, loadA<21, B3>(s3));  OBP(21, p21);

    V3 p22 = mulv_add(R20, loadOff(off, 22), p20);  OBP(22, p22); // hand leaf
    V3 p23 = mulv_add(R21, loadOff(off, 23), p21);  OBP(23, p23); // hand leaf

    // ---- transpose via LDS (reuses span1 region; same wave, in-order DS) ----
    asm volatile("" ::: "memory");
#pragma unroll
    for (int r = 0; r < 18; ++r) {
        float4 v;
        v.x = ob[4*r+0]; v.y = ob[4*r+1]; v.z = ob[4*r+2]; v.w = ob[4*r+3];
        stage[r * 65 + l] = v;                       // quad (r+l)%8: uniform, free
    }

    // ---- coalesced nontemporal output ----
    v4f* o4 = reinterpret_cast<v4f*>(out);
    const size_t base4 = blockBase * 18;
#pragma unroll
    for (int i = 0; i < 18; ++i) {
        int e4 = i * 64 + l;
        int s  = e4 / 18;                            // magic-mul div
        int r  = e4 - s * 18;
        float4 v = stage[r * 65 + s];
        v4f vv; vv.x = v.x; vv.y = v.y; vv.z = v.z; vv.w = v.w;
        __builtin_nontemporal_store(vv, &o4[base4 + e4]);
    }
}

}  // namespace

extern "C" void kernel_launch(void* const* d_in, const int* in_sizes, int n_in,
                              void* d_out, int out_size, void* d_ws, size_t ws_size,
                              hipStream_t stream) {
    const float* ja  = (const float*)d_in[0];
    const float* off = (const float*)d_in[1];
    float* out = (float*)d_out;

    int N = in_sizes[0] / 216;     // 262144
    int grid = N / 64;             // 4096 one-wave blocks
    hipLaunchKernelGGL(fk_kernel, dim3(grid), dim3(64), 0, stream, ja, off, out);
}